// Round 12
// baseline (276.331 us; speedup 1.0000x reference)
//
#include <hip/hip_runtime.h>
#include <hip/hip_bf16.h>

// MoE block: N=8192, D=1024, H=1024, E=16, top-k=2. Inputs fp32, output fp32.
// out[n] = w1*(x@W_e1 + b_e1) + w2*(x@W_e2 + b_e2), w = top-2 of softmax.
//
// Round-17: 8-wave GEMM blocks. R16 counters: GEMM 48.4us/pass with
// MfmaUtil 14%, VALUBusy 5.7%, occ 16.6%, FETCH 45MB (~ideal) -- latency
// bound: ~2.2 blocks/CU x 4 waves leaves the CU idle between the barrier /
// ds_read / MFMA phases. Fix: 512-thread blocks, 8 waves of 64x32 output
// (acc[4][2], 8 MFMA/step) on the same 128x128 tile -> ~16-18 waves/CU.
// Staging: one 32B row-half per thread, wave-uniform X/W split (tid>>8).
// All else (dbuf, 1 barrier/step, reg prefetch, XCD swizzle, worklist,
// router_lds, build_lists, cvt_w, fallback path) unchanged from R16 (passed).
//   pass A (ADD=0): slot-0 lists -> out = w*(x@W+b)   (covers every token)
//   pass B (ADD=1): slot-1 lists -> out += w*(x@W+b)  (fp32 RMW, race-free)

#define N_TOK 8192
#define D_DIM 1024
#define H_DIM 1024
#define E_NUM 16
#define CAP   1024
#define KPAD  40    // LDS row stride in ushorts (80 B = 16B*5: b128-aligned)

typedef __attribute__((ext_vector_type(4))) float f32x4;
typedef __attribute__((ext_vector_type(8))) short bf16x8;

__device__ __forceinline__ unsigned short f2bf(float f) {
    unsigned int u = __float_as_uint(f);
    unsigned int r = u + 0x7fffu + ((u >> 16) & 1u);   // RNE
    return (unsigned short)(r >> 16);
}
__device__ __forceinline__ unsigned int pk2bf(float lo, float hi) {
    return (unsigned int)f2bf(lo) | ((unsigned int)f2bf(hi) << 16);
}

// ---------------- router, LDS-staged x (+ bf16 X side-product) ----------------
__global__ __launch_bounds__(256) void router_lds(
    const float* __restrict__ x,
    const float* __restrict__ rw,
    const float* __restrict__ rb,
    int4* __restrict__ res,
    unsigned short* __restrict__ xb)
{
    __shared__ __align__(16) float xls[8][4][260];   // [row][stripe][pos]
    __shared__ double lg[4][2][E_NUM];

    const int tid = threadIdx.x;
    const int t0b = blockIdx.x * 8;

    // ---- phase 0: coalesced x read -> bf16 xb write + fp32 LDS stage
    {
        const int r   = tid >> 5;                 // 0..7  (block-local row)
        const int c32 = (tid & 31) * 32;          // 32 floats per thread
        const int s   = c32 >> 8;                 // stripe (constant per thread)
        const int p0  = c32 & 255;
        const float* src = x + (size_t)(t0b + r) * D_DIM + c32;
        float4 v[8];
#pragma unroll
        for (int j = 0; j < 8; ++j) v[j] = *(const float4*)(src + j * 4);
#pragma unroll
        for (int j = 0; j < 8; ++j)
            *(float4*)&xls[r][s][p0 + j * 4] = v[j];
        unsigned int q[16];
#pragma unroll
        for (int j = 0; j < 8; ++j) {
            q[2 * j]     = pk2bf(v[j].x, v[j].y);
            q[2 * j + 1] = pk2bf(v[j].z, v[j].w);
        }
        unsigned short* dst = xb + (size_t)(t0b + r) * D_DIM + c32;
        *(uint4*)(dst)      = *(uint4*)&q[0];
        *(uint4*)(dst + 8)  = *(uint4*)&q[4];
        *(uint4*)(dst + 16) = *(uint4*)&q[8];
        *(uint4*)(dst + 24) = *(uint4*)&q[12];
    }
    __syncthreads();

    // ---- phase 1: (ds,e) FMA chain, x from LDS (identical math to proven)
    const int wave = tid >> 6;
    const int lane = tid & 63;
    const int ds   = lane >> 4;
    const int e    = lane & 15;
    const int lr0  = wave * 2;                    // block-local token rows
    const float* rwp = rw + ds * 4096 + e;

    double acc0 = 0.0, acc1 = 0.0;
#pragma unroll 2
    for (int g = 0; g < 8; ++g) {
        float s0 = 0.0f, s1 = 0.0f;
#pragma unroll
        for (int u = 0; u < 8; ++u) {
            const int jb = g * 8 + u;
            const float4 a = *(const float4*)&xls[lr0][ds][jb * 4];
            const float4 b = *(const float4*)&xls[lr0 + 1][ds][jb * 4];
            const float w0 = rwp[jb * 64];
            const float w1 = rwp[jb * 64 + 16];
            const float w2 = rwp[jb * 64 + 32];
            const float w3 = rwp[jb * 64 + 48];
            s0 = fmaf(a.w, w3, fmaf(a.z, w2, fmaf(a.y, w1, fmaf(a.x, w0, s0))));
            s1 = fmaf(b.w, w3, fmaf(b.z, w2, fmaf(b.y, w1, fmaf(b.x, w0, s1))));
        }
        acc0 += (double)s0;
        acc1 += (double)s1;
    }

    double v0 = acc0, v1 = acc1;
    v0 += __shfl_xor(v0, 16); v0 += __shfl_xor(v0, 32);
    v1 += __shfl_xor(v1, 16); v1 += __shfl_xor(v1, 32);

    if (ds == 0) {
        const double bias = (double)rb[e];
        lg[wave][0][e] = v0 + bias;
        lg[wave][1][e] = v1 + bias;
    }
    __syncthreads();

    if (lane < 2) {
        const double* L = lg[wave][lane];
        double m = L[0];
#pragma unroll
        for (int k = 1; k < E_NUM; ++k) m = fmax(m, L[k]);

        int e1 = 0;
#pragma unroll
        for (int k = 1; k < E_NUM; ++k) if (L[k] > L[e1]) e1 = k;
        int e2 = (e1 == 0) ? 1 : 0;
        for (int k = 0; k < E_NUM; ++k)
            if (k != e1 && L[k] > L[e2]) e2 = k;

        float s = 0.0f;
#pragma unroll
        for (int k = 0; k < E_NUM; ++k) s = fmaf(expf((float)(L[k] - m)), 1.0f, s);
        const float w1 = expf((float)(L[e1] - m)) / s;
        const float w2 = expf((float)(L[e2] - m)) / s;

        const int n = t0b + wave * 2 + lane;
        res[n] = make_int4(e1, e2, __float_as_int(w1), __float_as_int(w2));
    }
}

// ---------------- fallback router (global-broadcast x, proven) ----------------
template <bool WRITE_XB>
__global__ __launch_bounds__(256, 4) void router_kernel(
    const float* __restrict__ x,
    const float* __restrict__ rw,
    const float* __restrict__ rb,
    int4* __restrict__ res,
    unsigned short* __restrict__ xb)
{
    const int wave = threadIdx.x >> 6;
    const int lane = threadIdx.x & 63;
    const int ds   = lane >> 4;
    const int e    = lane & 15;
    const int t0   = blockIdx.x * 8 + wave * 2;

    const float* x0  = x + (size_t)t0 * D_DIM + ds * 256;
    const float* x1  = x0 + D_DIM;
    const float* rwp = rw + ds * 4096 + e;

    double acc0 = 0.0, acc1 = 0.0;
#pragma unroll 2
    for (int g = 0; g < 8; ++g) {
        float s0 = 0.0f, s1 = 0.0f;
#pragma unroll
        for (int u = 0; u < 8; ++u) {
            const int jb = g * 8 + u;
            const float4 a = *(const float4*)(x0 + jb * 4);
            const float4 b = *(const float4*)(x1 + jb * 4);
            const float w0 = rwp[jb * 64];
            const float w1 = rwp[jb * 64 + 16];
            const float w2 = rwp[jb * 64 + 32];
            const float w3 = rwp[jb * 64 + 48];
            s0 = fmaf(a.w, w3, fmaf(a.z, w2, fmaf(a.y, w1, fmaf(a.x, w0, s0))));
            s1 = fmaf(b.w, w3, fmaf(b.z, w2, fmaf(b.y, w1, fmaf(b.x, w0, s1))));
        }
        acc0 += (double)s0;
        acc1 += (double)s1;
    }

    if (WRITE_XB) {
#pragma unroll
        for (int t = 0; t < 2; ++t) {
            const float* src = x + (size_t)(t0 + t) * D_DIM + lane * 16;
            unsigned short* dst = xb + (size_t)(t0 + t) * D_DIM + lane * 16;
            const float4 v0 = *(const float4*)(src);
            const float4 v1 = *(const float4*)(src + 4);
            const float4 v2 = *(const float4*)(src + 8);
            const float4 v3 = *(const float4*)(src + 12);
            uint4 lo, hi;
            lo.x = pk2bf(v0.x, v0.y); lo.y = pk2bf(v0.z, v0.w);
            lo.z = pk2bf(v1.x, v1.y); lo.w = pk2bf(v1.z, v1.w);
            hi.x = pk2bf(v2.x, v2.y); hi.y = pk2bf(v2.z, v2.w);
            hi.z = pk2bf(v3.x, v3.y); hi.w = pk2bf(v3.z, v3.w);
            *(uint4*)dst       = lo;
            *(uint4*)(dst + 8) = hi;
        }
    }

    double v0 = acc0, v1 = acc1;
    v0 += __shfl_xor(v0, 16); v0 += __shfl_xor(v0, 32);
    v1 += __shfl_xor(v1, 16); v1 += __shfl_xor(v1, 32);

    __shared__ double lg[4][2][E_NUM];
    if (ds == 0) {
        const double bias = (double)rb[e];
        lg[wave][0][e] = v0 + bias;
        lg[wave][1][e] = v1 + bias;
    }
    __syncthreads();

    if (lane < 2) {
        const double* L = lg[wave][lane];
        double m = L[0];
#pragma unroll
        for (int k = 1; k < E_NUM; ++k) m = fmax(m, L[k]);

        int e1 = 0;
#pragma unroll
        for (int k = 1; k < E_NUM; ++k) if (L[k] > L[e1]) e1 = k;
        int e2 = (e1 == 0) ? 1 : 0;
        for (int k = 0; k < E_NUM; ++k)
            if (k != e1 && L[k] > L[e2]) e2 = k;

        float s = 0.0f;
#pragma unroll
        for (int k = 0; k < E_NUM; ++k) s = fmaf(expf((float)(L[k] - m)), 1.0f, s);
        const float w1 = expf((float)(L[e1] - m)) / s;
        const float w2 = expf((float)(L[e2] - m)) / s;

        const int n = t0 + lane;
        res[n] = make_int4(e1, e2, __float_as_int(w1), __float_as_int(w2));
    }
}

// ---------------- build_lists (unchanged) ----------------
__global__ __launch_bounds__(256) void build_lists(
    const int4* __restrict__ res,
    int* __restrict__ counts0, int* __restrict__ counts1,
    int2* __restrict__ entries0, int2* __restrict__ entries1)
{
    const int e = blockIdx.x;
    __shared__ int c0, c1;
    if (threadIdx.x == 0) { c0 = 0; c1 = 0; }
    __syncthreads();

    for (int i = threadIdx.x; i < N_TOK; i += 256) {
        const int4 r = res[i];
        if (r.x == e) {
            int p = atomicAdd(&c0, 1);
            if (p < CAP) entries0[e * CAP + p] = make_int2(i, r.z);
        }
        if (r.y == e) {
            int p = atomicAdd(&c1, 1);
            if (p < CAP) entries1[e * CAP + p] = make_int2(i, r.w);
        }
    }
    __syncthreads();
    if (threadIdx.x == 0) { counts0[e] = c0; counts1[e] = c1; }
}

// ---------------- cvt: Wt = bf16(W) transposed [E][H][D] ----------------
__global__ __launch_bounds__(256) void cvt_w_kernel(
    const float* __restrict__ ew,
    unsigned short* __restrict__ wt)
{
    const int tid = threadIdx.x;
    __shared__ unsigned short Ts[64][68];
    const int wi = blockIdx.x;                // 0..4095
    const int e  = wi >> 8;                   // 256 tiles/expert
    const int kt = (wi >> 4) & 15;
    const int ht = wi & 15;

    // read: 64 k-rows x 64 h, coalesced float4, convert, store [k][h]
    {
        const int kl0 = tid >> 4;             // 0..15 (+16*i)
        const int hl  = (tid & 15) * 4;
        const float* src = ew + (size_t)e * (D_DIM * H_DIM)
                         + (size_t)(kt * 64 + kl0) * H_DIM + ht * 64 + hl;
#pragma unroll
        for (int i = 0; i < 4; ++i) {
            const float4 v = *(const float4*)(src + (size_t)i * 16 * H_DIM);
            ushort4 p;
            p.x = f2bf(v.x); p.y = f2bf(v.y); p.z = f2bf(v.z); p.w = f2bf(v.w);
            *(ushort4*)&Ts[kl0 + i * 16][hl] = p;
        }
    }
    __syncthreads();
    // write: 64 h-rows x 64 k, transposed gather from LDS, 32B/thread
    {
        const int h2 = tid >> 2;              // 0..63
        const int kc = (tid & 3) * 16;
        unsigned int r[8];
#pragma unroll
        for (int i = 0; i < 8; ++i)
            r[i] = (unsigned int)Ts[kc + 2 * i][h2]
                 | ((unsigned int)Ts[kc + 2 * i + 1][h2] << 16);
        unsigned short* dst = wt + (size_t)e * (D_DIM * H_DIM)
                            + (size_t)(ht * 64 + h2) * D_DIM + kt * 64 + kc;
        *(uint4*)dst       = *(uint4*)&r[0];
        *(uint4*)(dst + 8) = *(uint4*)&r[4];
    }
}

// ---------------- GEMM: bf16 precache, 8 waves, dense worklist + XCD swizzle ----------------
template <bool ADD>
__global__ __launch_bounds__(512) void moe_gemm_bf16(
    const unsigned short* __restrict__ xb,   // [N][D] bf16
    const unsigned short* __restrict__ wt,   // [E][H][D] bf16
    const float* __restrict__ eb,
    const int* __restrict__ counts,
    const int2* __restrict__ entries,
    float* __restrict__ out)
{
    // total active blocks T (uniform across blocks, from counts)
    int T = 0;
    for (int k = 0; k < E_NUM; ++k) {
        int c = counts[k]; if (c > CAP) c = CAP;
        T += ((c + 127) >> 7) << 3;            // ceil(c/128) * 8 h-blocks
    }
    if ((int)blockIdx.x >= T) return;

    // m204 bijective XCD swizzle over [0,T): b=8k+xcd -> contiguous loc
    // chunk per XCD, so the 8 h-blocks sharing an X tile stay on one XCD.
    const int q = T >> 3, r = T & 7;
    const int xcd = blockIdx.x & 7;
    int loc = (xcd < r ? xcd * (q + 1) : r * (q + 1) + (xcd - r) * q)
            + (blockIdx.x >> 3);

    // walk: loc -> (e, i-chunk, h)
    int e = 0, count = 0;
    for (; e < E_NUM; ++e) {
        int c = counts[e]; if (c > CAP) c = CAP;
        const int nb = ((c + 127) >> 7) << 3;
        if (loc < nb) { count = c; break; }
        loc -= nb;
    }
    const int i0 = (loc >> 3) * 128;
    const int h0 = (loc & 7) * 128;

    __shared__ unsigned short Xs[2][128][KPAD];
    __shared__ unsigned short Ws[2][128][KPAD];
    __shared__ int   s_tok[128];
    __shared__ float s_w[128];

    const int tid = threadIdx.x;
    if (tid < 128) {
        const int i = i0 + tid;
        if (i < count) {
            int2 en = entries[e * CAP + i];
            s_tok[tid] = en.x;
            s_w[tid] = __int_as_float(en.y);
        } else {
            s_tok[tid] = 0;
            s_w[tid] = 0.0f;
        }
    }
    __syncthreads();

    const int wave = tid >> 6;                 // 0..7
    const int lane = tid & 63;
    const int wr = (wave >> 2) * 64;           // token-row offset (0/64)
    const int wc = (wave & 3) * 32;            // h-col offset (0/32/64/96)
    const int l15 = lane & 15;
    const int quad = lane >> 4;

    f32x4 acc[4][2] = {};                      // 64x32 per wave

    // staging map: thread -> (array, row 0..127, 16-ushort half). tid>>8 is
    // wave-uniform (waves 0-3 stage X, waves 4-7 stage W).
    const int arr  = tid >> 8;                 // 0 = X, 1 = W
    const int row  = (tid & 255) >> 1;
    const int half = (tid & 1) * 16;
    const unsigned short* gp = (arr == 0)
        ? xb + (size_t)s_tok[row] * D_DIM + half
        : wt + (size_t)(e * H_DIM + h0 + row) * D_DIM + half;
    unsigned short* lds0 = (arr == 0) ? &Xs[0][row][half] : &Ws[0][row][half];
    unsigned short* lds1 = (arr == 0) ? &Xs[1][row][half] : &Ws[1][row][half];

    // prefetch tile 0 -> regs -> buf 0
    uint4 p0 = *(const uint4*)(gp);
    uint4 p1 = *(const uint4*)(gp + 8);
    *(uint4*)(lds0)     = p0;
    *(uint4*)(lds0 + 8) = p1;

    int cur = 0;
    for (int d0 = 0; d0 < D_DIM; d0 += 32) {
        __syncthreads();                       // buf[cur] ready
        const bool more = (d0 + 32 < D_DIM);

        if (more) {                            // issue next-tile loads
            p0 = *(const uint4*)(gp + d0 + 32);
            p1 = *(const uint4*)(gp + d0 + 40);
        }

        bf16x8 af[4], bq[2];
#pragma unroll
        for (int i = 0; i < 4; ++i)
            af[i] = *(const bf16x8*)&Xs[cur][wr + i * 16 + l15][quad * 8];
#pragma unroll
        for (int j = 0; j < 2; ++j)
            bq[j] = *(const bf16x8*)&Ws[cur][wc + j * 16 + l15][quad * 8];
#pragma unroll
        for (int i = 0; i < 4; ++i)
#pragma unroll
            for (int j = 0; j < 2; ++j)
                acc[i][j] = __builtin_amdgcn_mfma_f32_16x16x32_bf16(
                    af[i], bq[j], acc[i][j], 0, 0, 0);

        if (more) {                            // write next tile
            unsigned short* dst = cur ? lds0 : lds1;
            *(uint4*)(dst)     = p0;
            *(uint4*)(dst + 8) = p1;
        }
        cur ^= 1;
    }

    float bias_j[2];
    const float* ebp = eb + e * H_DIM + h0 + wc;
#pragma unroll
    for (int j = 0; j < 2; ++j) bias_j[j] = ebp[j * 16 + l15];

#pragma unroll
    for (int i = 0; i < 4; ++i) {
#pragma unroll
        for (int r2 = 0; r2 < 4; ++r2) {
            const int orow = wr + i * 16 + quad * 4 + r2;
            if (i0 + orow < count) {
                const int tok = s_tok[orow];
                const float w = s_w[orow];
                float* op = out + (size_t)tok * H_DIM + h0 + wc + l15;
#pragma unroll
                for (int j = 0; j < 2; ++j) {
                    float v = w * (acc[i][j][r2] + bias_j[j]);
                    if (ADD) v += op[j * 16];
                    op[j * 16] = v;
                }
            }
        }
    }
}

// ---------------- fallback GEMM (fp32 staging — proven) ----------------
template <bool ADD>
__global__ __launch_bounds__(256) void moe_mfma_kernel(
    const float* __restrict__ x,
    const float* __restrict__ ew,
    const float* __restrict__ eb,
    const int* __restrict__ counts,
    const int2* __restrict__ entries,
    float* __restrict__ out)
{
    const int flat = blockIdx.x;
    const int lid  = (flat & 7) * 128 + (flat >> 3);
    const int h0 = (lid & 7) * 128;
    const int i0 = ((lid >> 3) & 7) * 128;
    const int e  = lid >> 6;

    int count = counts[e];
    if (count > CAP) count = CAP;
    if (i0 >= count) return;

    __shared__ unsigned short Xs[2][128][KPAD];
    __shared__ unsigned short Ws[2][128][KPAD];
    __shared__ int   s_tok[128];
    __shared__ float s_w[128];

    const int tid = threadIdx.x;
    if (tid < 128) {
        const int i = i0 + tid;
        if (i < count) {
            int2 en = entries[e * CAP + i];
            s_tok[tid] = en.x;
            s_w[tid] = __int_as_float(en.y);
        } else {
            s_tok[tid] = 0;
            s_w[tid] = 0.0f;
        }
    }
    __syncthreads();

    const int wave = tid >> 6;
    const int lane = tid & 63;
    const int wr = (wave >> 1) * 64;
    const int wc = (wave & 1) * 64;
    const int l15 = lane & 15;
    const int quad = lane >> 4;

    f32x4 acc[4][4] = {};

    const int a_kq = (tid & 7) * 4;
    const int a_r0 = tid >> 3;
    const int b_n  = tid & 127;
    const int b_dh = (tid >> 7) * 16;

    const float* ap[4];
#pragma unroll
    for (int it = 0; it < 4; ++it)
        ap[it] = x + (size_t)s_tok[a_r0 + it * 32] * D_DIM + a_kq;
    const float* bp = ew + (size_t)e * D_DIM * H_DIM
                    + (size_t)b_dh * H_DIM + h0 + b_n;

    float4 pa[4];
    float  pb[16];
#pragma unroll
    for (int it = 0; it < 4; ++it) pa[it] = *(const float4*)(ap[it]);
#pragma unroll
    for (int i = 0; i < 16; ++i)  pb[i] = bp[(size_t)i * H_DIM];

    {
#pragma unroll
        for (int it = 0; it < 4; ++it) {
            ushort4 p;
            p.x = f2bf(pa[it].x); p.y = f2bf(pa[it].y);
            p.z = f2bf(pa[it].z); p.w = f2bf(pa[it].w);
            *(ushort4*)&Xs[0][a_r0 + it * 32][a_kq] = p;
        }
        uint4 lo, hi;
        lo.x = pk2bf(pb[0], pb[1]);   lo.y = pk2bf(pb[2], pb[3]);
        lo.z = pk2bf(pb[4], pb[5]);   lo.w = pk2bf(pb[6], pb[7]);
        hi.x = pk2bf(pb[8], pb[9]);   hi.y = pk2bf(pb[10], pb[11]);
        hi.z = pk2bf(pb[12], pb[13]); hi.w = pk2bf(pb[14], pb[15]);
        *(uint4*)&Ws[0][b_n][b_dh]     = lo;
        *(uint4*)&Ws[0][b_n][b_dh + 8] = hi;
    }

    int cur = 0;
    for (int d0 = 0; d0 < D_DIM; d0 += 32) {
        __syncthreads();
        const bool more = (d0 + 32 < D_DIM);

        if (more) {
#pragma unroll
            for (int it = 0; it < 4; ++it)
                pa[it] = *(const float4*)(ap[it] + d0 + 32);
#pragma unroll
            for (int i = 0; i < 16; ++i)
                pb[i] = bp[(size_t)(d0 + 32 + i) * H_DIM];
        }

        bf16x8 af[4], bq[4];
#pragma unroll
        for (int i = 0; i < 4; ++i)
            af[i] = *(const bf16x8*)&Xs[cur][wr + i * 16 + l15][quad * 8];
#pragma unroll
        for (int j = 0; j < 4; ++j)
            bq[j] = *(const bf16x8*)&Ws[cur][wc + j * 16 + l15][quad * 8];
#pragma unroll
        for (int i = 0; i < 4; ++i)
#pragma unroll
            for (int j = 0; j < 4; ++j)
                acc[i][j] = __builtin_amdgcn_mfma_f32_16x16x32_bf16(
                    af[i], bq[j], acc[i][j], 0, 0, 0);

        if (more) {
            const int nxt = cur ^ 1;
#pragma unroll
            for (int it = 0; it < 4; ++it) {
                ushort4 p;
                p.x = f2bf(pa[it].x); p.y = f2bf(pa[it].y);
                p.z = f2bf(pa[it].z); p.w = f2bf(pa[it].w);
                *(ushort4*)&Xs[nxt][a_r0 + it * 32][a_kq] = p;
            }
            uint4 lo, hi;
            lo.x = pk2bf(pb[0], pb[1]);   lo.y = pk2bf(pb[2], pb[3]);
            lo.z = pk2bf(pb[4], pb[5]);   lo.w = pk2bf(pb[6], pb[7]);
            hi.x = pk2bf(pb[8], pb[9]);   hi.y = pk2bf(pb[10], pb[11]);
            hi.z = pk2bf(pb[12], pb[13]); hi.w = pk2bf(pb[14], pb[15]);
            *(uint4*)&Ws[nxt][b_n][b_dh]     = lo;
            *(uint4*)&Ws[nxt][b_n][b_dh + 8] = hi;
        }
        cur ^= 1;
    }

    float bias_j[4];
    const float* ebp = eb + e * H_DIM + h0 + wc;
#pragma unroll
    for (int j = 0; j < 4; ++j) bias_j[j] = ebp[j * 16 + l15];

#pragma unroll
    for (int i = 0; i < 4; ++i) {
#pragma unroll
        for (int r2 = 0; r2 < 4; ++r2) {
            const int orow = wr + i * 16 + quad * 4 + r2;
            if (i0 + orow < count) {
                const int tok = s_tok[orow];
                const float w = s_w[orow];
                float* op = out + (size_t)tok * H_DIM + h0 + wc + l15;
#pragma unroll
                for (int j = 0; j < 4; ++j) {
                    float v = w * (acc[i][j][r2] + bias_j[j]);
                    if (ADD) v += op[j * 16];
                    op[j * 16] = v;
                }
            }
        }
    }
}

extern "C" void kernel_launch(void* const* d_in, const int* in_sizes, int n_in,
                              void* d_out, int out_size, void* d_ws, size_t ws_size,
                              hipStream_t stream)
{
    const float* x  = (const float*)d_in[0];
    const float* rw = (const float*)d_in[1];
    const float* rb = (const float*)d_in[2];
    const float* ew = (const float*)d_in[3];
    const float* eb = (const float*)d_in[4];

    char* ws = (char*)d_ws;
    int*  counts0  = (int*)ws;
    int*  counts1  = (int*)(ws + 64);
    int2* entries0 = (int2*)(ws + 1024);
    int2* entries1 = (int2*)(ws + 1024 + E_NUM * CAP * 8);

    // bf16 precache region (guarded by ws_size)
    const size_t XB_OFF = (size_t)1 << 20;                       // 1 MB
    const size_t XB_SZ  = (size_t)N_TOK * D_DIM * 2;             // 16 MB
    const size_t WT_OFF = XB_OFF + XB_SZ;
    const size_t WT_SZ  = (size_t)E_NUM * D_DIM * H_DIM * 2;     // 32 MB
    const bool precache = ws_size >= WT_OFF + WT_SZ;

    // res[] staged in d_out (128 KB of the 32 MB output buffer). Stream
    // order: router writes res -> build_lists consumes -> pass A overwrites
    // every token row.
    int4* res = (int4*)d_out;

    if (precache) {
        unsigned short* xbp = (unsigned short*)(ws + XB_OFF);
        unsigned short* wtp = (unsigned short*)(ws + WT_OFF);
        router_lds<<<N_TOK / 8, 256, 0, stream>>>(x, rw, rb, res, xbp);
        build_lists<<<E_NUM, 256, 0, stream>>>(res, counts0, counts1,
                                               entries0, entries1);
        cvt_w_kernel<<<4096, 256, 0, stream>>>(ew, wtp);
        moe_gemm_bf16<false><<<1024, 512, 0, stream>>>(
            xbp, wtp, eb, counts0, entries0, (float*)d_out);
        moe_gemm_bf16<true><<<1024, 512, 0, stream>>>(
            xbp, wtp, eb, counts1, entries1, (float*)d_out);
    } else {
        router_kernel<false><<<N_TOK / 8, 256, 0, stream>>>(x, rw, rb, res, nullptr);
        build_lists<<<E_NUM, 256, 0, stream>>>(res, counts0, counts1,
                                               entries0, entries1);
        moe_mfma_kernel<false><<<1024, 256, 0, stream>>>(
            x, ew, eb, counts0, entries0, (float*)d_out);
        moe_mfma_kernel<true><<<1024, 256, 0, stream>>>(
            x, ew, eb, counts1, entries1, (float*)d_out);
    }
}